// Round 10
// baseline (355.208 us; speedup 1.0000x reference)
//
#include <hip/hip_runtime.h>

// GraphNet forward on MI355X — Round 10: G2 fragment double-buffer (LDS/MFMA
// pipe overlap) + vectorized transpose.
// Cycle model (round-9 counters): per K-tile/CU LDS 384cy + MFMA 310cy were
// SERIALIZED by lockstep barrier (775cy measured). This round overlaps them:
// ds_read frags(t+1) issued before MFMA(t), counted lgkmcnt(12), single
// barrier/tile, vmcnt certify-before-barrier (validated round-9 pattern).
//  T1: eW1 -> eW1T [4096,160] bf16 | T2: eW2 -> eW2T bf16 (u64 writes)
//  E : ein bf16 | G1: h = relu(ein@eW1+eb1) (128^2, validated)
//  G2: new_edges = relu(h@eW2+eb2) -> d_out f32 (256^2, frag-dbuf pipeline)
//  S : accb += scatter(new_edges @ nWmT^T) (MFMA) | N : node MLP (validated)
typedef unsigned short u16;
typedef unsigned int u32;
typedef unsigned long long u64;
typedef __bf16 bf16x8 __attribute__((ext_vector_type(8)));
typedef float f32x4 __attribute__((ext_vector_type(4)));

static __device__ __forceinline__ float bf2f(u16 u) {
  return __uint_as_float(((u32)u) << 16);
}
static __device__ __forceinline__ u16 f2bf(float f) {
  u32 x = __float_as_uint(f);
  return (u16)((x + 0x7fffu + ((x >> 16) & 1u)) >> 16);  // RNE
}
static __device__ __forceinline__ void gl_lds16(const u16* g, u16* l) {
  __builtin_amdgcn_global_load_lds(
      (const __attribute__((address_space(1))) void*)g,
      (__attribute__((address_space(3))) void*)l, 16, 0, 0);
}
static __device__ __forceinline__ u64 pack4bf(f32x4 v) {
  u64 r = (u64)f2bf(v[0]);
  r |= (u64)f2bf(v[1]) << 16;
  r |= (u64)f2bf(v[2]) << 32;
  r |= (u64)f2bf(v[3]) << 48;
  return r;
}

// ---------- transpose f32[K][N] -> bf16[N][Kpad], vectorized both sides ----------
__global__ __launch_bounds__(256) void k_transpose(const float* __restrict__ in,
                                                   u16* __restrict__ out,
                                                   int K, int N, int Kpad) {
  __shared__ u16 t[64 * 68];
  const int tid = threadIdx.x;
  const int k0 = blockIdx.x * 64, n0 = blockIdx.y * 64;
#pragma unroll
  for (int pass = 0; pass < 4; pass++) {
    int ki = pass * 16 + (tid >> 4);
    int nj = (tid & 15) * 4;
    f32x4 v = {0.f, 0.f, 0.f, 0.f};
    if (k0 + ki < K) v = *(const f32x4*)&in[(long)(k0 + ki) * N + n0 + nj];
    *(u64*)&t[ki * 68 + nj] = pack4bf(v);
  }
  __syncthreads();
#pragma unroll
  for (int pass = 0; pass < 4; pass++) {
    int ni = pass * 16 + (tid >> 4);
    int kj = (tid & 15) * 4;
    if (k0 + kj < Kpad) {
      u64 w = (u64)t[(kj + 0) * 68 + ni] | ((u64)t[(kj + 1) * 68 + ni] << 16) |
              ((u64)t[(kj + 2) * 68 + ni] << 32) | ((u64)t[(kj + 3) * 68 + ni] << 48);
      *(u64*)&out[(long)(n0 + ni) * Kpad + k0 + kj] = w;
    }
  }
}

// ---------- e_in builder: [4096][160] bf16 ----------
__global__ __launch_bounds__(192) void k_build_ein(const float* __restrict__ edges,
                                                   const float* __restrict__ nodes,
                                                   const float* __restrict__ g,
                                                   const int* __restrict__ senders,
                                                   const int* __restrict__ receivers,
                                                   u16* __restrict__ ein) {
  const int e = blockIdx.x;
  const int x = threadIdx.x;
  if (x >= 160) return;
  const int s = senders[e], r = receivers[e];
  float v;
  if (x < 16) v = edges[(long)e * 16 + x];
  else if (x < 80) v = nodes[(long)s * 64 + (x - 16)];
  else if (x < 144) v = nodes[(long)r * 64 + (x - 80)];
  else if (x < 152) v = g[x - 144];
  else v = 0.f;
  ein[(long)e * 160 + x] = f2bf(v);
}

// ---------- 128^2 MFMA GEMM (G1, round-9 validated) ----------
template <int MODE>
__global__ __launch_bounds__(256) void k_mgemm(const u16* __restrict__ A,
                                               const u16* __restrict__ BT,
                                               const float* __restrict__ bias,
                                               void* __restrict__ C, int M, int N, int K) {
  __shared__ alignas(16) u16 As[128 * 32];
  __shared__ alignas(16) u16 Bs[128 * 32];
  const int tid = threadIdx.x;
  const int lane = tid & 63, wid = tid >> 6;
  const int wr = wid >> 1, wc = wid & 1;
  const int m0 = blockIdx.x * 128, n0 = blockIdx.y * 128;
  const int lr = lane & 15, lk = lane >> 4;
  const int swz = (lk ^ ((lr >> 1) & 3)) << 3;
  const int srow = tid >> 2;
  const int skk = ((tid & 3) ^ ((tid >> 3) & 3)) << 3;

  f32x4 acc[4][4];
#pragma unroll
  for (int i = 0; i < 4; i++)
#pragma unroll
    for (int j = 0; j < 4; j++) acc[i][j] = {0.f, 0.f, 0.f, 0.f};

  for (int kt = 0; kt < K; kt += 32) {
#pragma unroll
    for (int rep = 0; rep < 2; rep++) {
      int row = rep * 64 + srow;
      int o = rep * 2048 + tid * 8;
      gl_lds16(&A[(long)(m0 + row) * K + kt + skk], &As[o]);
      gl_lds16(&BT[(long)(n0 + row) * K + kt + skk], &Bs[o]);
    }
    __syncthreads();
    bf16x8 af[4], bfr[4];
#pragma unroll
    for (int mi = 0; mi < 4; mi++)
      af[mi] = *(const bf16x8*)&As[(wr * 64 + mi * 16 + lr) * 32 + swz];
#pragma unroll
    for (int ni = 0; ni < 4; ni++)
      bfr[ni] = *(const bf16x8*)&Bs[(wc * 64 + ni * 16 + lr) * 32 + swz];
#pragma unroll
    for (int mi = 0; mi < 4; mi++)
#pragma unroll
      for (int ni = 0; ni < 4; ni++)
        acc[mi][ni] =
            __builtin_amdgcn_mfma_f32_16x16x32_bf16(af[mi], bfr[ni], acc[mi][ni], 0, 0, 0);
    __syncthreads();
  }
#pragma unroll
  for (int ni = 0; ni < 4; ni++) {
    int col = n0 + wc * 64 + ni * 16 + lr;
    float bb = bias[col];
#pragma unroll
    for (int mi = 0; mi < 4; mi++) {
      int row = m0 + wr * 64 + mi * 16 + lk * 4;
#pragma unroll
      for (int r = 0; r < 4; r++) {
        float v = fmaxf(acc[mi][ni][r] + bb, 0.f);
        if (MODE == 0) ((u16*)C)[(long)(row + r) * N + col] = f2bf(v);
        else ((float*)C)[(long)(row + r) * N + col] = v;
      }
    }
  }
}

// ---------- 256^2 G2 with fragment double-buffer ----------
// Per tile u: vmcnt(4) certifies own G(u+1) BEFORE barrier (publish);
// STAGE(u+3) -> buf (u-1)&3 (readers done: frags(u-1) reads completed by
// iter u-1's lgkmcnt(12), which precedes this barrier); ds_read frags(u+1);
// lgkmcnt(12) = frags(u) ready, frags(u+1) in flight; MFMA(u) overlaps reads.
// Ledger (NT=128): prologue STAGE 0,1,2 -> vmcnt(8)=G(0); iter u outstanding
// at vmcnt = G(u+1),G(u+2) (8 ops) -> vmcnt(4)=G(u+1). Tail: u=125 vmcnt(4),
// u=126 vmcnt(0), u=127 lgkmcnt(0) only. K MUST be 4096.
__global__ __launch_bounds__(512, 1) void k_gemm256(const u16* __restrict__ A,
                                                    const u16* __restrict__ BT,
                                                    const float* __restrict__ bias,
                                                    float* __restrict__ C, int N, int K) {
  __shared__ alignas(16) u16 lds[65536];  // 4 bufs x (A 8192 + B 8192) u16
  const int tid = threadIdx.x;
  const int lane = tid & 63, wid = tid >> 6;
  const int wr = wid >> 2, wc = wid & 3;
  const int m0 = blockIdx.x * 256, n0 = blockIdx.y * 256;
  const int lr = lane & 15, lk = lane >> 4;
  const int swz = (lk ^ ((lr >> 1) & 3)) << 3;

  const int srow = wid * 16 + (lane >> 2);
  const int sq = ((lane & 3) ^ ((lane >> 3) & 3)) << 3;
  const int sdst = wid * 512 + lane * 8;
  const u16* As0 = &A[(long)(m0 + srow) * K + sq];
  const u16* As1 = &A[(long)(m0 + 128 + srow) * K + sq];
  const u16* Bs0 = &BT[(long)(n0 + srow) * K + sq];
  const u16* Bs1 = &BT[(long)(n0 + 128 + srow) * K + sq];

  f32x4 acc[8][4];
#pragma unroll
  for (int i = 0; i < 8; i++)
#pragma unroll
    for (int j = 0; j < 4; j++) acc[i][j] = {0.f, 0.f, 0.f, 0.f};

  bf16x8 afA[8], bfA[4], afB[8], bfB[4];

#define G2_STAGE(T, BUF)                                   \
  {                                                        \
    const int kt_ = (T) * 32;                              \
    u16* b_ = &lds[(BUF) * 16384];                         \
    gl_lds16(As0 + kt_, b_ + sdst);                        \
    gl_lds16(As1 + kt_, b_ + 4096 + sdst);                 \
    gl_lds16(Bs0 + kt_, b_ + 8192 + sdst);                 \
    gl_lds16(Bs1 + kt_, b_ + 12288 + sdst);                \
  }

#define G2_READF(AF, BF, BUF)                                                     \
  {                                                                               \
    const u16* Ab_ = &lds[(BUF) * 16384];                                         \
    const u16* Bb_ = Ab_ + 8192;                                                  \
    _Pragma("unroll") for (int mi = 0; mi < 8; mi++)                              \
        AF[mi] = *(const bf16x8*)&Ab_[(wr * 128 + mi * 16 + lr) * 32 + swz];      \
    _Pragma("unroll") for (int ni = 0; ni < 4; ni++)                              \
        BF[ni] = *(const bf16x8*)&Bb_[(wc * 64 + ni * 16 + lr) * 32 + swz];       \
  }

#define G2_MFMA(AF, BF)                                                            \
  {                                                                                \
    __builtin_amdgcn_s_setprio(1);                                                 \
    _Pragma("unroll") for (int mi = 0; mi < 8; mi++)                               \
        _Pragma("unroll") for (int ni = 0; ni < 4; ni++)                           \
            acc[mi][ni] = __builtin_amdgcn_mfma_f32_16x16x32_bf16(AF[mi], BF[ni],  \
                                                                  acc[mi][ni],    \
                                                                  0, 0, 0);        \
    __builtin_amdgcn_s_setprio(0);                                                 \
  }

#define G2_SUB(CA, CB, NA, NB, BUFN, TS, SBUF)             \
  asm volatile("s_waitcnt vmcnt(4)" ::: "memory");         \
  __builtin_amdgcn_s_barrier();                            \
  G2_STAGE(TS, SBUF);                                      \
  G2_READF(NA, NB, BUFN);                                  \
  asm volatile("s_waitcnt lgkmcnt(12)" ::: "memory");      \
  __builtin_amdgcn_sched_barrier(0);                       \
  G2_MFMA(CA, CB);

  // prologue: stage tiles 0..2, certify G(0), publish, read frags(0)
  G2_STAGE(0, 0)
  G2_STAGE(1, 1)
  G2_STAGE(2, 2)
  asm volatile("s_waitcnt vmcnt(8)" ::: "memory");
  __builtin_amdgcn_s_barrier();
  G2_READF(afA, bfA, 0)

  // steady state: u = 0..123 (NT=128), 4-way unroll, bufs static
  for (int t = 0; t < 124; t += 4) {
    G2_SUB(afA, bfA, afB, bfB, 1, t + 3, 3)  // u=t
    G2_SUB(afB, bfB, afA, bfA, 2, t + 4, 0)  // u=t+1
    G2_SUB(afA, bfA, afB, bfB, 3, t + 5, 1)  // u=t+2
    G2_SUB(afB, bfB, afA, bfA, 0, t + 6, 2)  // u=t+3
  }
  // u=124: last full sub-iter (stages tile 127 into buf 3)
  G2_SUB(afA, bfA, afB, bfB, 1, 127, 3)
  // u=125: no stage; outstanding G(126),G(127)=8 -> vmcnt(4) lands G(126)
  asm volatile("s_waitcnt vmcnt(4)" ::: "memory");
  __builtin_amdgcn_s_barrier();
  G2_READF(afA, bfA, 2)
  asm volatile("s_waitcnt lgkmcnt(12)" ::: "memory");
  __builtin_amdgcn_sched_barrier(0);
  G2_MFMA(afB, bfB)
  // u=126: outstanding G(127)=4 -> vmcnt(0)
  asm volatile("s_waitcnt vmcnt(0)" ::: "memory");
  __builtin_amdgcn_s_barrier();
  G2_READF(afB, bfB, 3)
  asm volatile("s_waitcnt lgkmcnt(12)" ::: "memory");
  __builtin_amdgcn_sched_barrier(0);
  G2_MFMA(afA, bfA)
  // u=127: final tile, frags already read
  asm volatile("s_waitcnt lgkmcnt(0)" ::: "memory");
  __builtin_amdgcn_sched_barrier(0);
  G2_MFMA(afB, bfB)

#undef G2_SUB
#undef G2_MFMA
#undef G2_READF
#undef G2_STAGE

#pragma unroll
  for (int ni = 0; ni < 4; ni++) {
    int col = n0 + wc * 64 + ni * 16 + lr;
    float bb = bias[col];
#pragma unroll
    for (int mi = 0; mi < 8; mi++) {
      int row = m0 + wr * 128 + mi * 16 + lk * 4;
#pragma unroll
      for (int r = 0; r < 4; r++)
        C[(long)(row + r) * N + col] = fmaxf(acc[mi][ni][r] + bb, 0.f);
    }
  }
}

// ---------- MFMA scatter-GEMM (round-9 validated) ----------
__global__ __launch_bounds__(256) void k_scatter_m(const float* __restrict__ E,
                                                   const u16* __restrict__ BT,
                                                   const int* __restrict__ senders,
                                                   const int* __restrict__ receivers,
                                                   float* __restrict__ accb) {
  const int K = 4096;
  __shared__ alignas(16) u16 As[128 * 32];
  __shared__ alignas(16) u16 Bs[128 * 32];
  const int tid = threadIdx.x;
  const int lane = tid & 63, wid = tid >> 6;
  const int wr = wid >> 1, wc = wid & 1;
  const int m0 = blockIdx.x * 128;
  const int kbase = blockIdx.y * 512;
  const int lr = lane & 15, lk = lane >> 4;
  const int swz = (lk ^ ((lr >> 1) & 3)) << 3;
  const int srow = tid >> 2;
  const int skk = ((tid & 3) ^ ((tid >> 3) & 3)) << 3;

  f32x4 acc[4][4];
#pragma unroll
  for (int i = 0; i < 4; i++)
#pragma unroll
    for (int j = 0; j < 4; j++) acc[i][j] = {0.f, 0.f, 0.f, 0.f};

  for (int kt = kbase; kt < kbase + 512; kt += 32) {
#pragma unroll
    for (int p = 0; p < 4; p++) {
      int idx = p * 256 + tid;
      int r = idx >> 3;
      int kq = idx & 7;
      f32x4 v = *(const f32x4*)&E[(long)(m0 + r) * 4096 + kt + kq * 4];
      int gq = (kq >> 1) ^ ((r >> 1) & 3);
      *(u64*)&As[r * 32 + gq * 8 + (kq & 1) * 4] = pack4bf(v);
    }
#pragma unroll
    for (int rep = 0; rep < 2; rep++) {
      int row = rep * 64 + srow;
      gl_lds16(&BT[(long)row * K + kt + skk], &Bs[rep * 2048 + tid * 8]);
    }
    __syncthreads();
    bf16x8 af[4], bfr[4];
#pragma unroll
    for (int mi = 0; mi < 4; mi++)
      af[mi] = *(const bf16x8*)&As[(wr * 64 + mi * 16 + lr) * 32 + swz];
#pragma unroll
    for (int ni = 0; ni < 4; ni++)
      bfr[ni] = *(const bf16x8*)&Bs[(wc * 64 + ni * 16 + lr) * 32 + swz];
#pragma unroll
    for (int mi = 0; mi < 4; mi++)
#pragma unroll
      for (int ni = 0; ni < 4; ni++)
        acc[mi][ni] =
            __builtin_amdgcn_mfma_f32_16x16x32_bf16(af[mi], bfr[ni], acc[mi][ni], 0, 0, 0);
    __syncthreads();
  }
#pragma unroll
  for (int mi = 0; mi < 4; mi++) {
#pragma unroll
    for (int r = 0; r < 4; r++) {
      int e = m0 + wr * 64 + mi * 16 + lk * 4 + r;
#pragma unroll
      for (int ni = 0; ni < 4; ni++) {
        int col = wc * 64 + ni * 16 + lr;
        int tgt = (col < 64) ? senders[e] : receivers[e];
        atomicAdd(&accb[(long)tgt * 64 + (col & 63)], acc[mi][ni][r]);
      }
    }
  }
}

// ---------- final node MLP, pure f32 (round-6 validated) ----------
__global__ __launch_bounds__(256) void k_final(const float* __restrict__ nodes,
                                               const float* __restrict__ g,
                                               const float* __restrict__ nW1,
                                               const float* __restrict__ nb1,
                                               const float* __restrict__ nW2,
                                               const float* __restrict__ nb2,
                                               const float* __restrict__ zpre,
                                               float* __restrict__ out0) {
  __shared__ float h2[64 * 64];
  __shared__ float gb[64];
  const int tid = threadIdx.x;
  const long n0 = (long)blockIdx.x * 64;
  if (tid < 64) {
    float s = nb1[tid];
#pragma unroll
    for (int j = 0; j < 8; j++) s += g[j] * nW1[(long)(8256 + j) * 64 + tid];
    gb[tid] = s;
  }
  __syncthreads();
#pragma unroll 2
  for (int rep = 0; rep < 16; rep++) {
    int idx = rep * 256 + tid;
    int i = idx >> 6, c = idx & 63;
    float z = gb[c] + zpre[(n0 + i) * 64 + c];
    const float* nr = nodes + (n0 + i) * 64;
#pragma unroll 8
    for (int k = 0; k < 64; k++) z += nr[k] * nW1[(long)k * 64 + c];
    h2[idx] = fmaxf(z, 0.f);
  }
  __syncthreads();
#pragma unroll 2
  for (int rep = 0; rep < 16; rep++) {
    int idx = rep * 256 + tid;
    int i = idx >> 6, c = idx & 63;
    float z = nb2[c];
#pragma unroll 8
    for (int k = 0; k < 64; k++) z += h2[i * 64 + k] * nW2[(long)k * 64 + c];
    out0[(n0 + i) * 64 + c] = fmaxf(z, 0.f);
  }
}

extern "C" void kernel_launch(void* const* d_in, const int* in_sizes, int n_in,
                              void* d_out, int out_size, void* d_ws, size_t ws_size,
                              hipStream_t stream) {
  const float* nodes = (const float*)d_in[0];
  const float* edges = (const float*)d_in[1];
  const float* g = (const float*)d_in[2];
  const int* senders = (const int*)d_in[3];
  const int* receivers = (const int*)d_in[4];
  const float* eW1 = (const float*)d_in[5];
  const float* eb1 = (const float*)d_in[6];
  const float* eW2 = (const float*)d_in[7];
  const float* eb2 = (const float*)d_in[8];
  const float* nW1 = (const float*)d_in[9];
  const float* nb1 = (const float*)d_in[10];
  const float* nW2 = (const float*)d_in[11];
  const float* nb2 = (const float*)d_in[12];

  char* ws = (char*)d_ws;
  u16* eW1T = (u16*)(ws + 0);        // [4096][160] bf16, dies after G1
  float* accb = (float*)(ws + 0);    // [8192][64] f32, live after memset (post-G1)
  u16* ein = (u16*)(ws + 2097152);   // [4096][160] bf16, dies after G1
  u16* nWmT = (u16*)(ws + 2097152);  // [128][4096] bf16, written after G1
  u16* eW2T = (u16*)(ws + 3407872);  // [4096][4096] bf16
  u16* h = (u16*)(ws + 36962304);    // [4096][4096] bf16 (ends 70.5MB)

  float* out_nodes = (float*)d_out;
  float* out_edges = (float*)d_out + 524288;

  dim3 b256(256);
  k_transpose<<<dim3(3, 64), b256, 0, stream>>>(eW1, eW1T, 152, 4096, 160);
  k_transpose<<<dim3(64, 64), b256, 0, stream>>>(eW2, eW2T, 4096, 4096, 4096);
  k_build_ein<<<4096, 192, 0, stream>>>(edges, nodes, g, senders, receivers, ein);

  k_mgemm<0><<<dim3(32, 32), b256, 0, stream>>>(ein, eW1T, eb1, h, 4096, 4096, 160);

  // ein/eW1T dead: build nWmT + clear accb before scatter.
  k_transpose<<<dim3(64, 1), b256, 0, stream>>>(nW1 + 64 * 64, nWmT, 4096, 64, 4096);
  k_transpose<<<dim3(64, 1), b256, 0, stream>>>(nW1 + 4160 * 64, nWmT + (long)64 * 4096,
                                                4096, 64, 4096);
  hipMemsetAsync(accb, 0, 8192 * 64 * 4, stream);

  k_gemm256<<<dim3(16, 16), dim3(512), 0, stream>>>(h, eW2T, eb2, out_edges, 4096, 4096);

  k_scatter_m<<<dim3(32, 8), b256, 0, stream>>>(out_edges, nWmT, senders, receivers, accb);
  k_final<<<128, b256, 0, stream>>>(nodes, g, nW1, nb1, nW2, nb2, accb, out_nodes);
}

// Round 11
// 252.399 us; speedup vs baseline: 1.4073x; 1.4073x over previous
//
#include <hip/hip_runtime.h>

// GraphNet forward on MI355X — Round 11: revert G2 to round-9 schedule (round-10
// sched_barrier pinning = m141 failure mode, -107us) + XCD-aware block swizzle.
//  T1: eW1 -> eW1T [4096,160] bf16 | T2: eW2 -> eW2T bf16 (vectorized, r10)
//  E : ein bf16 | G1: h = relu(ein@eW1+eb1) (128^2, validated)
//  G2: new_edges = relu(h@eW2+eb2) -> d_out f32 (256^2, 4-buf pipeline,
//      counted vmcnt, 1 barrier/K-tile = round-9-validated; NEW: 1D grid with
//      bijective XCD swizzle — XCD c owns 2 A-panels (4MB = L2), streams B)
//  S : accb += scatter(new_edges @ nWmT^T) (MFMA, validated)
//  N : node MLP (validated)
typedef unsigned short u16;
typedef unsigned int u32;
typedef unsigned long long u64;
typedef __bf16 bf16x8 __attribute__((ext_vector_type(8)));
typedef float f32x4 __attribute__((ext_vector_type(4)));

static __device__ __forceinline__ float bf2f(u16 u) {
  return __uint_as_float(((u32)u) << 16);
}
static __device__ __forceinline__ u16 f2bf(float f) {
  u32 x = __float_as_uint(f);
  return (u16)((x + 0x7fffu + ((x >> 16) & 1u)) >> 16);  // RNE
}
static __device__ __forceinline__ void gl_lds16(const u16* g, u16* l) {
  __builtin_amdgcn_global_load_lds(
      (const __attribute__((address_space(1))) void*)g,
      (__attribute__((address_space(3))) void*)l, 16, 0, 0);
}
static __device__ __forceinline__ u64 pack4bf(f32x4 v) {
  u64 r = (u64)f2bf(v[0]);
  r |= (u64)f2bf(v[1]) << 16;
  r |= (u64)f2bf(v[2]) << 32;
  r |= (u64)f2bf(v[3]) << 48;
  return r;
}

// ---------- transpose f32[K][N] -> bf16[N][Kpad] (round-10 validated) ----------
__global__ __launch_bounds__(256) void k_transpose(const float* __restrict__ in,
                                                   u16* __restrict__ out,
                                                   int K, int N, int Kpad) {
  __shared__ u16 t[64 * 68];
  const int tid = threadIdx.x;
  const int k0 = blockIdx.x * 64, n0 = blockIdx.y * 64;
#pragma unroll
  for (int pass = 0; pass < 4; pass++) {
    int ki = pass * 16 + (tid >> 4);
    int nj = (tid & 15) * 4;
    f32x4 v = {0.f, 0.f, 0.f, 0.f};
    if (k0 + ki < K) v = *(const f32x4*)&in[(long)(k0 + ki) * N + n0 + nj];
    *(u64*)&t[ki * 68 + nj] = pack4bf(v);
  }
  __syncthreads();
#pragma unroll
  for (int pass = 0; pass < 4; pass++) {
    int ni = pass * 16 + (tid >> 4);
    int kj = (tid & 15) * 4;
    if (k0 + kj < Kpad) {
      u64 w = (u64)t[(kj + 0) * 68 + ni] | ((u64)t[(kj + 1) * 68 + ni] << 16) |
              ((u64)t[(kj + 2) * 68 + ni] << 32) | ((u64)t[(kj + 3) * 68 + ni] << 48);
      *(u64*)&out[(long)(n0 + ni) * Kpad + k0 + kj] = w;
    }
  }
}

// ---------- e_in builder: [4096][160] bf16 ----------
__global__ __launch_bounds__(192) void k_build_ein(const float* __restrict__ edges,
                                                   const float* __restrict__ nodes,
                                                   const float* __restrict__ g,
                                                   const int* __restrict__ senders,
                                                   const int* __restrict__ receivers,
                                                   u16* __restrict__ ein) {
  const int e = blockIdx.x;
  const int x = threadIdx.x;
  if (x >= 160) return;
  const int s = senders[e], r = receivers[e];
  float v;
  if (x < 16) v = edges[(long)e * 16 + x];
  else if (x < 80) v = nodes[(long)s * 64 + (x - 16)];
  else if (x < 144) v = nodes[(long)r * 64 + (x - 80)];
  else if (x < 152) v = g[x - 144];
  else v = 0.f;
  ein[(long)e * 160 + x] = f2bf(v);
}

// ---------- 128^2 MFMA GEMM (G1, validated) ----------
template <int MODE>
__global__ __launch_bounds__(256) void k_mgemm(const u16* __restrict__ A,
                                               const u16* __restrict__ BT,
                                               const float* __restrict__ bias,
                                               void* __restrict__ C, int M, int N, int K) {
  __shared__ alignas(16) u16 As[128 * 32];
  __shared__ alignas(16) u16 Bs[128 * 32];
  const int tid = threadIdx.x;
  const int lane = tid & 63, wid = tid >> 6;
  const int wr = wid >> 1, wc = wid & 1;
  const int m0 = blockIdx.x * 128, n0 = blockIdx.y * 128;
  const int lr = lane & 15, lk = lane >> 4;
  const int swz = (lk ^ ((lr >> 1) & 3)) << 3;
  const int srow = tid >> 2;
  const int skk = ((tid & 3) ^ ((tid >> 3) & 3)) << 3;

  f32x4 acc[4][4];
#pragma unroll
  for (int i = 0; i < 4; i++)
#pragma unroll
    for (int j = 0; j < 4; j++) acc[i][j] = {0.f, 0.f, 0.f, 0.f};

  for (int kt = 0; kt < K; kt += 32) {
#pragma unroll
    for (int rep = 0; rep < 2; rep++) {
      int row = rep * 64 + srow;
      int o = rep * 2048 + tid * 8;
      gl_lds16(&A[(long)(m0 + row) * K + kt + skk], &As[o]);
      gl_lds16(&BT[(long)(n0 + row) * K + kt + skk], &Bs[o]);
    }
    __syncthreads();
    bf16x8 af[4], bfr[4];
#pragma unroll
    for (int mi = 0; mi < 4; mi++)
      af[mi] = *(const bf16x8*)&As[(wr * 64 + mi * 16 + lr) * 32 + swz];
#pragma unroll
    for (int ni = 0; ni < 4; ni++)
      bfr[ni] = *(const bf16x8*)&Bs[(wc * 64 + ni * 16 + lr) * 32 + swz];
#pragma unroll
    for (int mi = 0; mi < 4; mi++)
#pragma unroll
      for (int ni = 0; ni < 4; ni++)
        acc[mi][ni] =
            __builtin_amdgcn_mfma_f32_16x16x32_bf16(af[mi], bfr[ni], acc[mi][ni], 0, 0, 0);
    __syncthreads();
  }
#pragma unroll
  for (int ni = 0; ni < 4; ni++) {
    int col = n0 + wc * 64 + ni * 16 + lr;
    float bb = bias[col];
#pragma unroll
    for (int mi = 0; mi < 4; mi++) {
      int row = m0 + wr * 64 + mi * 16 + lk * 4;
#pragma unroll
      for (int r = 0; r < 4; r++) {
        float v = fmaxf(acc[mi][ni][r] + bb, 0.f);
        if (MODE == 0) ((u16*)C)[(long)(row + r) * N + col] = f2bf(v);
        else ((float*)C)[(long)(row + r) * N + col] = v;
      }
    }
  }
}

// ---------- 256^2 G2: round-9 schedule + XCD swizzle ----------
// 1D grid 256. XCD c = orig&7 (HW round-robin) owns logical j=orig>>3 in
// [0,32): mx = 2c + (j>>4), ny = j&15  -> 2 A-panels (4MB) resident per L2,
// B streamed via L3. Bijective. Pipeline identical to round 9 (validated):
// 4 LDS bufs, stage lead 3, vmcnt(8)/(4)/(0), one s_barrier per K-tile.
__global__ __launch_bounds__(512, 1) void k_gemm256(const u16* __restrict__ A,
                                                    const u16* __restrict__ BT,
                                                    const float* __restrict__ bias,
                                                    float* __restrict__ C, int N, int K) {
  __shared__ alignas(16) u16 lds[65536];  // 128 KB
  const int tid = threadIdx.x;
  const int lane = tid & 63, wid = tid >> 6;
  const int wr = wid >> 2, wc = wid & 3;
  const int orig = blockIdx.x;
  const int xc = orig & 7, jj = orig >> 3;
  const int m0 = (2 * xc + (jj >> 4)) * 256;
  const int n0 = (jj & 15) * 256;
  const int lr = lane & 15, lk = lane >> 4;
  const int swz = (lk ^ ((lr >> 1) & 3)) << 3;
  const int NT = K >> 5;

  const int srow = wid * 16 + (lane >> 2);
  const int sq = ((lane & 3) ^ ((lane >> 3) & 3)) << 3;
  const int sdst = wid * 512 + lane * 8;

  f32x4 acc[8][4];
#pragma unroll
  for (int i = 0; i < 8; i++)
#pragma unroll
    for (int j = 0; j < 4; j++) acc[i][j] = {0.f, 0.f, 0.f, 0.f};

#define STAGE_TILE(T)                                                              \
  {                                                                                \
    const int kt_ = (T) * 32;                                                      \
    u16* Ab_ = &lds[((T) & 3) * 16384];                                            \
    u16* Bb_ = Ab_ + 8192;                                                         \
    gl_lds16(&A[(long)(m0 + srow) * K + kt_ + sq], Ab_ + sdst);                    \
    gl_lds16(&A[(long)(m0 + 128 + srow) * K + kt_ + sq], Ab_ + 4096 + sdst);       \
    gl_lds16(&BT[(long)(n0 + srow) * K + kt_ + sq], Bb_ + sdst);                   \
    gl_lds16(&BT[(long)(n0 + 128 + srow) * K + kt_ + sq], Bb_ + 4096 + sdst);      \
  }

  STAGE_TILE(0)
  STAGE_TILE(1)
  STAGE_TILE(2)

  for (int t = 0; t < NT; t++) {
    if (t < NT - 2) {
      asm volatile("s_waitcnt vmcnt(8)" ::: "memory");
    } else if (t == NT - 2) {
      asm volatile("s_waitcnt vmcnt(4)" ::: "memory");
    } else {
      asm volatile("s_waitcnt vmcnt(0)" ::: "memory");
    }
    __builtin_amdgcn_s_barrier();
    if (t + 3 < NT) STAGE_TILE(t + 3)

    const u16* Ab = &lds[(t & 3) * 16384];
    const u16* Bb = Ab + 8192;
    bf16x8 af[8], bfr[4];
#pragma unroll
    for (int mi = 0; mi < 8; mi++)
      af[mi] = *(const bf16x8*)&Ab[(wr * 128 + mi * 16 + lr) * 32 + swz];
#pragma unroll
    for (int ni = 0; ni < 4; ni++)
      bfr[ni] = *(const bf16x8*)&Bb[(wc * 64 + ni * 16 + lr) * 32 + swz];
#pragma unroll
    for (int mi = 0; mi < 8; mi++)
#pragma unroll
      for (int ni = 0; ni < 4; ni++)
        acc[mi][ni] =
            __builtin_amdgcn_mfma_f32_16x16x32_bf16(af[mi], bfr[ni], acc[mi][ni], 0, 0, 0);
  }
#undef STAGE_TILE

#pragma unroll
  for (int ni = 0; ni < 4; ni++) {
    int col = n0 + wc * 64 + ni * 16 + lr;
    float bb = bias[col];
#pragma unroll
    for (int mi = 0; mi < 8; mi++) {
      int row = m0 + wr * 128 + mi * 16 + lk * 4;
#pragma unroll
      for (int r = 0; r < 4; r++)
        C[(long)(row + r) * N + col] = fmaxf(acc[mi][ni][r] + bb, 0.f);
    }
  }
}

// ---------- MFMA scatter-GEMM (validated) ----------
__global__ __launch_bounds__(256) void k_scatter_m(const float* __restrict__ E,
                                                   const u16* __restrict__ BT,
                                                   const int* __restrict__ senders,
                                                   const int* __restrict__ receivers,
                                                   float* __restrict__ accb) {
  const int K = 4096;
  __shared__ alignas(16) u16 As[128 * 32];
  __shared__ alignas(16) u16 Bs[128 * 32];
  const int tid = threadIdx.x;
  const int lane = tid & 63, wid = tid >> 6;
  const int wr = wid >> 1, wc = wid & 1;
  const int m0 = blockIdx.x * 128;
  const int kbase = blockIdx.y * 512;
  const int lr = lane & 15, lk = lane >> 4;
  const int swz = (lk ^ ((lr >> 1) & 3)) << 3;
  const int srow = tid >> 2;
  const int skk = ((tid & 3) ^ ((tid >> 3) & 3)) << 3;

  f32x4 acc[4][4];
#pragma unroll
  for (int i = 0; i < 4; i++)
#pragma unroll
    for (int j = 0; j < 4; j++) acc[i][j] = {0.f, 0.f, 0.f, 0.f};

  for (int kt = kbase; kt < kbase + 512; kt += 32) {
#pragma unroll
    for (int p = 0; p < 4; p++) {
      int idx = p * 256 + tid;
      int r = idx >> 3;
      int kq = idx & 7;
      f32x4 v = *(const f32x4*)&E[(long)(m0 + r) * 4096 + kt + kq * 4];
      int gq = (kq >> 1) ^ ((r >> 1) & 3);
      *(u64*)&As[r * 32 + gq * 8 + (kq & 1) * 4] = pack4bf(v);
    }
#pragma unroll
    for (int rep = 0; rep < 2; rep++) {
      int row = rep * 64 + srow;
      gl_lds16(&BT[(long)row * K + kt + skk], &Bs[rep * 2048 + tid * 8]);
    }
    __syncthreads();
    bf16x8 af[4], bfr[4];
#pragma unroll
    for (int mi = 0; mi < 4; mi++)
      af[mi] = *(const bf16x8*)&As[(wr * 64 + mi * 16 + lr) * 32 + swz];
#pragma unroll
    for (int ni = 0; ni < 4; ni++)
      bfr[ni] = *(const bf16x8*)&Bs[(wc * 64 + ni * 16 + lr) * 32 + swz];
#pragma unroll
    for (int mi = 0; mi < 4; mi++)
#pragma unroll
      for (int ni = 0; ni < 4; ni++)
        acc[mi][ni] =
            __builtin_amdgcn_mfma_f32_16x16x32_bf16(af[mi], bfr[ni], acc[mi][ni], 0, 0, 0);
    __syncthreads();
  }
#pragma unroll
  for (int mi = 0; mi < 4; mi++) {
#pragma unroll
    for (int r = 0; r < 4; r++) {
      int e = m0 + wr * 64 + mi * 16 + lk * 4 + r;
#pragma unroll
      for (int ni = 0; ni < 4; ni++) {
        int col = wc * 64 + ni * 16 + lr;
        int tgt = (col < 64) ? senders[e] : receivers[e];
        atomicAdd(&accb[(long)tgt * 64 + (col & 63)], acc[mi][ni][r]);
      }
    }
  }
}

// ---------- final node MLP, pure f32 (validated) ----------
__global__ __launch_bounds__(256) void k_final(const float* __restrict__ nodes,
                                               const float* __restrict__ g,
                                               const float* __restrict__ nW1,
                                               const float* __restrict__ nb1,
                                               const float* __restrict__ nW2,
                                               const float* __restrict__ nb2,
                                               const float* __restrict__ zpre,
                                               float* __restrict__ out0) {
  __shared__ float h2[64 * 64];
  __shared__ float gb[64];
  const int tid = threadIdx.x;
  const long n0 = (long)blockIdx.x * 64;
  if (tid < 64) {
    float s = nb1[tid];
#pragma unroll
    for (int j = 0; j < 8; j++) s += g[j] * nW1[(long)(8256 + j) * 64 + tid];
    gb[tid] = s;
  }
  __syncthreads();
#pragma unroll 2
  for (int rep = 0; rep < 16; rep++) {
    int idx = rep * 256 + tid;
    int i = idx >> 6, c = idx & 63;
    float z = gb[c] + zpre[(n0 + i) * 64 + c];
    const float* nr = nodes + (n0 + i) * 64;
#pragma unroll 8
    for (int k = 0; k < 64; k++) z += nr[k] * nW1[(long)k * 64 + c];
    h2[idx] = fmaxf(z, 0.f);
  }
  __syncthreads();
#pragma unroll 2
  for (int rep = 0; rep < 16; rep++) {
    int idx = rep * 256 + tid;
    int i = idx >> 6, c = idx & 63;
    float z = nb2[c];
#pragma unroll 8
    for (int k = 0; k < 64; k++) z += h2[i * 64 + k] * nW2[(long)k * 64 + c];
    out0[(n0 + i) * 64 + c] = fmaxf(z, 0.f);
  }
}

extern "C" void kernel_launch(void* const* d_in, const int* in_sizes, int n_in,
                              void* d_out, int out_size, void* d_ws, size_t ws_size,
                              hipStream_t stream) {
  const float* nodes = (const float*)d_in[0];
  const float* edges = (const float*)d_in[1];
  const float* g = (const float*)d_in[2];
  const int* senders = (const int*)d_in[3];
  const int* receivers = (const int*)d_in[4];
  const float* eW1 = (const float*)d_in[5];
  const float* eb1 = (const float*)d_in[6];
  const float* eW2 = (const float*)d_in[7];
  const float* eb2 = (const float*)d_in[8];
  const float* nW1 = (const float*)d_in[9];
  const float* nb1 = (const float*)d_in[10];
  const float* nW2 = (const float*)d_in[11];
  const float* nb2 = (const float*)d_in[12];

  char* ws = (char*)d_ws;
  u16* eW1T = (u16*)(ws + 0);        // [4096][160] bf16, dies after G1
  float* accb = (float*)(ws + 0);    // [8192][64] f32, live after memset (post-G1)
  u16* ein = (u16*)(ws + 2097152);   // [4096][160] bf16, dies after G1
  u16* nWmT = (u16*)(ws + 2097152);  // [128][4096] bf16, written after G1
  u16* eW2T = (u16*)(ws + 3407872);  // [4096][4096] bf16
  u16* h = (u16*)(ws + 36962304);    // [4096][4096] bf16 (ends 70.5MB)

  float* out_nodes = (float*)d_out;
  float* out_edges = (float*)d_out + 524288;

  dim3 b256(256);
  k_transpose<<<dim3(3, 64), b256, 0, stream>>>(eW1, eW1T, 152, 4096, 160);
  k_transpose<<<dim3(64, 64), b256, 0, stream>>>(eW2, eW2T, 4096, 4096, 4096);
  k_build_ein<<<4096, 192, 0, stream>>>(edges, nodes, g, senders, receivers, ein);

  k_mgemm<0><<<dim3(32, 32), b256, 0, stream>>>(ein, eW1T, eb1, h, 4096, 4096, 160);

  // ein/eW1T dead: build nWmT + clear accb before scatter.
  k_transpose<<<dim3(64, 1), b256, 0, stream>>>(nW1 + 64 * 64, nWmT, 4096, 64, 4096);
  k_transpose<<<dim3(64, 1), b256, 0, stream>>>(nW1 + 4160 * 64, nWmT + (long)64 * 4096,
                                                4096, 64, 4096);
  hipMemsetAsync(accb, 0, 8192 * 64 * 4, stream);

  k_gemm256<<<dim3(256), dim3(512), 0, stream>>>(h, eW2T, eb2, out_edges, 4096, 4096);

  k_scatter_m<<<dim3(32, 8), b256, 0, stream>>>(out_edges, nWmT, senders, receivers, accb);
  k_final<<<128, b256, 0, stream>>>(nodes, g, nW1, nb1, nW2, nb2, accb, out_nodes);
}

// Round 12
// 251.136 us; speedup vs baseline: 1.4144x; 1.0050x over previous
//
#include <hip/hip_runtime.h>

// GraphNet forward on MI355X — Round 12: G2 -> BK=64, 2-buf, 2-phase/K-step
// (T3/T4/T5 mechanism as minimal delta from validated round-9 schedule).
// Per iter t (K=64): vmcnt(8) [counted; t landed, t+1 in flight] -> barrier ->
//   phase ks=0: 12 ds_read_b128 -> lgkmcnt(0)+sched_barrier(0) [rule 18] ->
//               setprio(1) 32 MFMA setprio(0)
//   phase ks=1: same
// -> barrier -> stage(t+2) [8 gl_lds, overwrites buf[t&1]; safe: all reads of
//    buf[t&1] lgkm-completed before barrier#2].
// Swizzle (128B rows): read slot g^(row&7); stage source granule
// (tid&7)^((tid>>3)&7) — involution, same family as r9's conflict-free scheme.
// Rest of pipeline unchanged (validated rounds 6-11). Output f32; ws 70.5MB.
typedef unsigned short u16;
typedef unsigned int u32;
typedef unsigned long long u64;
typedef __bf16 bf16x8 __attribute__((ext_vector_type(8)));
typedef float f32x4 __attribute__((ext_vector_type(4)));

static __device__ __forceinline__ float bf2f(u16 u) {
  return __uint_as_float(((u32)u) << 16);
}
static __device__ __forceinline__ u16 f2bf(float f) {
  u32 x = __float_as_uint(f);
  return (u16)((x + 0x7fffu + ((x >> 16) & 1u)) >> 16);  // RNE
}
static __device__ __forceinline__ void gl_lds16(const u16* g, u16* l) {
  __builtin_amdgcn_global_load_lds(
      (const __attribute__((address_space(1))) void*)g,
      (__attribute__((address_space(3))) void*)l, 16, 0, 0);
}
static __device__ __forceinline__ u64 pack4bf(f32x4 v) {
  u64 r = (u64)f2bf(v[0]);
  r |= (u64)f2bf(v[1]) << 16;
  r |= (u64)f2bf(v[2]) << 32;
  r |= (u64)f2bf(v[3]) << 48;
  return r;
}

// ---------- transpose f32[K][N] -> bf16[N][Kpad] (validated r10) ----------
__global__ __launch_bounds__(256) void k_transpose(const float* __restrict__ in,
                                                   u16* __restrict__ out,
                                                   int K, int N, int Kpad) {
  __shared__ u16 t[64 * 68];
  const int tid = threadIdx.x;
  const int k0 = blockIdx.x * 64, n0 = blockIdx.y * 64;
#pragma unroll
  for (int pass = 0; pass < 4; pass++) {
    int ki = pass * 16 + (tid >> 4);
    int nj = (tid & 15) * 4;
    f32x4 v = {0.f, 0.f, 0.f, 0.f};
    if (k0 + ki < K) v = *(const f32x4*)&in[(long)(k0 + ki) * N + n0 + nj];
    *(u64*)&t[ki * 68 + nj] = pack4bf(v);
  }
  __syncthreads();
#pragma unroll
  for (int pass = 0; pass < 4; pass++) {
    int ni = pass * 16 + (tid >> 4);
    int kj = (tid & 15) * 4;
    if (k0 + kj < Kpad) {
      u64 w = (u64)t[(kj + 0) * 68 + ni] | ((u64)t[(kj + 1) * 68 + ni] << 16) |
              ((u64)t[(kj + 2) * 68 + ni] << 32) | ((u64)t[(kj + 3) * 68 + ni] << 48);
      *(u64*)&out[(long)(n0 + ni) * Kpad + k0 + kj] = w;
    }
  }
}

// ---------- e_in builder: [4096][160] bf16 ----------
__global__ __launch_bounds__(192) void k_build_ein(const float* __restrict__ edges,
                                                   const float* __restrict__ nodes,
                                                   const float* __restrict__ g,
                                                   const int* __restrict__ senders,
                                                   const int* __restrict__ receivers,
                                                   u16* __restrict__ ein) {
  const int e = blockIdx.x;
  const int x = threadIdx.x;
  if (x >= 160) return;
  const int s = senders[e], r = receivers[e];
  float v;
  if (x < 16) v = edges[(long)e * 16 + x];
  else if (x < 80) v = nodes[(long)s * 64 + (x - 16)];
  else if (x < 144) v = nodes[(long)r * 64 + (x - 80)];
  else if (x < 152) v = g[x - 144];
  else v = 0.f;
  ein[(long)e * 160 + x] = f2bf(v);
}

// ---------- 128^2 MFMA GEMM (G1, validated) ----------
template <int MODE>
__global__ __launch_bounds__(256) void k_mgemm(const u16* __restrict__ A,
                                               const u16* __restrict__ BT,
                                               const float* __restrict__ bias,
                                               void* __restrict__ C, int M, int N, int K) {
  __shared__ alignas(16) u16 As[128 * 32];
  __shared__ alignas(16) u16 Bs[128 * 32];
  const int tid = threadIdx.x;
  const int lane = tid & 63, wid = tid >> 6;
  const int wr = wid >> 1, wc = wid & 1;
  const int m0 = blockIdx.x * 128, n0 = blockIdx.y * 128;
  const int lr = lane & 15, lk = lane >> 4;
  const int swz = (lk ^ ((lr >> 1) & 3)) << 3;
  const int srow = tid >> 2;
  const int skk = ((tid & 3) ^ ((tid >> 3) & 3)) << 3;

  f32x4 acc[4][4];
#pragma unroll
  for (int i = 0; i < 4; i++)
#pragma unroll
    for (int j = 0; j < 4; j++) acc[i][j] = {0.f, 0.f, 0.f, 0.f};

  for (int kt = 0; kt < K; kt += 32) {
#pragma unroll
    for (int rep = 0; rep < 2; rep++) {
      int row = rep * 64 + srow;
      int o = rep * 2048 + tid * 8;
      gl_lds16(&A[(long)(m0 + row) * K + kt + skk], &As[o]);
      gl_lds16(&BT[(long)(n0 + row) * K + kt + skk], &Bs[o]);
    }
    __syncthreads();
    bf16x8 af[4], bfr[4];
#pragma unroll
    for (int mi = 0; mi < 4; mi++)
      af[mi] = *(const bf16x8*)&As[(wr * 64 + mi * 16 + lr) * 32 + swz];
#pragma unroll
    for (int ni = 0; ni < 4; ni++)
      bfr[ni] = *(const bf16x8*)&Bs[(wc * 64 + ni * 16 + lr) * 32 + swz];
#pragma unroll
    for (int mi = 0; mi < 4; mi++)
#pragma unroll
      for (int ni = 0; ni < 4; ni++)
        acc[mi][ni] =
            __builtin_amdgcn_mfma_f32_16x16x32_bf16(af[mi], bfr[ni], acc[mi][ni], 0, 0, 0);
    __syncthreads();
  }
#pragma unroll
  for (int ni = 0; ni < 4; ni++) {
    int col = n0 + wc * 64 + ni * 16 + lr;
    float bb = bias[col];
#pragma unroll
    for (int mi = 0; mi < 4; mi++) {
      int row = m0 + wr * 64 + mi * 16 + lk * 4;
#pragma unroll
      for (int r = 0; r < 4; r++) {
        float v = fmaxf(acc[mi][ni][r] + bb, 0.f);
        if (MODE == 0) ((u16*)C)[(long)(row + r) * N + col] = f2bf(v);
        else ((float*)C)[(long)(row + r) * N + col] = v;
      }
    }
  }
}

// ---------- 256^2 G2: BK=64, 2-buf, 2-phase per K-step ----------
__global__ __launch_bounds__(512, 1) void k_gemm256(const u16* __restrict__ A,
                                                    const u16* __restrict__ BT,
                                                    const float* __restrict__ bias,
                                                    float* __restrict__ C, int N, int K) {
  __shared__ alignas(16) u16 lds[65536];  // 2 bufs x (A 256x64 + B 256x64) bf16 = 128KB
  const int tid = threadIdx.x;
  const int lane = tid & 63, wid = tid >> 6;
  const int wr = wid >> 2, wc = wid & 3;
  const int orig = blockIdx.x;
  const int xc = orig & 7, jj = orig >> 3;
  const int m0 = (2 * xc + (jj >> 4)) * 256;
  const int n0 = (jj & 15) * 256;
  const int lr = lane & 15, lk = lane >> 4;
  const int NT = K >> 6;  // 64

  // stage mapping: issue i covers rows i*64 + (tid>>3); source granule is the
  // inverse swizzle so linear-DMA'd LDS reads back correctly with g^(row&7).
  const int sgran = ((tid & 7) ^ ((tid >> 3) & 7)) << 3;  // u16 offset in row
  const int sdst = tid * 8;                               // u16 linear LDS offset
  const long abase = (long)(m0 + (tid >> 3)) * K + sgran;
  const long bbase = (long)(n0 + (tid >> 3)) * K + sgran;

  f32x4 acc[8][4];
#pragma unroll
  for (int i = 0; i < 8; i++)
#pragma unroll
    for (int j = 0; j < 4; j++) acc[i][j] = {0.f, 0.f, 0.f, 0.f};

#define STAGE64(T, BUF)                                     \
  {                                                         \
    const long ko_ = (long)(T) * 64;                        \
    u16* Ab_ = &lds[(BUF) * 32768];                         \
    u16* Bb_ = Ab_ + 16384;                                 \
    gl_lds16(&A[abase + ko_], Ab_ + sdst);                  \
    gl_lds16(&A[abase + (long)64 * K + ko_], Ab_ + 4096 + sdst);   \
    gl_lds16(&A[abase + (long)128 * K + ko_], Ab_ + 8192 + sdst);  \
    gl_lds16(&A[abase + (long)192 * K + ko_], Ab_ + 12288 + sdst); \
    gl_lds16(&BT[bbase + ko_], Bb_ + sdst);                 \
    gl_lds16(&BT[bbase + (long)64 * K + ko_], Bb_ + 4096 + sdst);  \
    gl_lds16(&BT[bbase + (long)128 * K + ko_], Bb_ + 8192 + sdst); \
    gl_lds16(&BT[bbase + (long)192 * K + ko_], Bb_ + 12288 + sdst);\
  }

// read offset (u16) of logical granule G in row R (row stride 64 u16 = 128B)
#define RSWZ(R, G) (((R) * 64) + ((((G) ^ ((R) & 7))) << 3))

#define PHASE(KS, AbP, BbP)                                                        \
  {                                                                                \
    bf16x8 af[8], bfr[4];                                                          \
    _Pragma("unroll") for (int mi = 0; mi < 8; mi++)                               \
        af[mi] = *(const bf16x8*)&AbP[RSWZ(wr * 128 + mi * 16 + lr, lk + 4 * (KS))]; \
    _Pragma("unroll") for (int ni = 0; ni < 4; ni++)                               \
        bfr[ni] = *(const bf16x8*)&BbP[RSWZ(wc * 64 + ni * 16 + lr, lk + 4 * (KS))]; \
    asm volatile("s_waitcnt lgkmcnt(0)" ::: "memory");                             \
    __builtin_amdgcn_sched_barrier(0);                                             \
    __builtin_amdgcn_s_setprio(1);                                                 \
    _Pragma("unroll") for (int mi = 0; mi < 8; mi++)                               \
        _Pragma("unroll") for (int ni = 0; ni < 4; ni++)                           \
            acc[mi][ni] = __builtin_amdgcn_mfma_f32_16x16x32_bf16(af[mi], bfr[ni], \
                                                                  acc[mi][ni],    \
                                                                  0, 0, 0);        \
    __builtin_amdgcn_s_setprio(0);                                                 \
  }

  // prologue: stage K-steps 0 and 1 (16 loads outstanding)
  STAGE64(0, 0)
  STAGE64(1, 1)

  for (int t = 0; t < NT; t++) {
    if (t == NT - 1) {
      asm volatile("s_waitcnt vmcnt(0)" ::: "memory");
    } else {
      asm volatile("s_waitcnt vmcnt(8)" ::: "memory");  // K-step t landed
    }
    __builtin_amdgcn_s_barrier();
    const u16* Ab = &lds[(t & 1) * 32768];
    const u16* Bb = Ab + 16384;
    PHASE(0, Ab, Bb)
    PHASE(1, Ab, Bb)
    __builtin_amdgcn_s_barrier();  // all reads of buf[t&1] done chip-wide
    if (t + 2 < NT) STAGE64(t + 2, t & 1)
  }
#undef PHASE
#undef RSWZ
#undef STAGE64

#pragma unroll
  for (int ni = 0; ni < 4; ni++) {
    int col = n0 + wc * 64 + ni * 16 + lr;
    float bb = bias[col];
#pragma unroll
    for (int mi = 0; mi < 8; mi++) {
      int row = m0 + wr * 128 + mi * 16 + lk * 4;
#pragma unroll
      for (int r = 0; r < 4; r++)
        C[(long)(row + r) * N + col] = fmaxf(acc[mi][ni][r] + bb, 0.f);
    }
  }
}

// ---------- MFMA scatter-GEMM (validated) ----------
__global__ __launch_bounds__(256) void k_scatter_m(const float* __restrict__ E,
                                                   const u16* __restrict__ BT,
                                                   const int* __restrict__ senders,
                                                   const int* __restrict__ receivers,
                                                   float* __restrict__ accb) {
  const int K = 4096;
  __shared__ alignas(16) u16 As[128 * 32];
  __shared__ alignas(16) u16 Bs[128 * 32];
  const int tid = threadIdx.x;
  const int lane = tid & 63, wid = tid >> 6;
  const int wr = wid >> 1, wc = wid & 1;
  const int m0 = blockIdx.x * 128;
  const int kbase = blockIdx.y * 512;
  const int lr = lane & 15, lk = lane >> 4;
  const int swz = (lk ^ ((lr >> 1) & 3)) << 3;
  const int srow = tid >> 2;
  const int skk = ((tid & 3) ^ ((tid >> 3) & 3)) << 3;

  f32x4 acc[4][4];
#pragma unroll
  for (int i = 0; i < 4; i++)
#pragma unroll
    for (int j = 0; j < 4; j++) acc[i][j] = {0.f, 0.f, 0.f, 0.f};

  for (int kt = kbase; kt < kbase + 512; kt += 32) {
#pragma unroll
    for (int p = 0; p < 4; p++) {
      int idx = p * 256 + tid;
      int r = idx >> 3;
      int kq = idx & 7;
      f32x4 v = *(const f32x4*)&E[(long)(m0 + r) * 4096 + kt + kq * 4];
      int gq = (kq >> 1) ^ ((r >> 1) & 3);
      *(u64*)&As[r * 32 + gq * 8 + (kq & 1) * 4] = pack4bf(v);
    }
#pragma unroll
    for (int rep = 0; rep < 2; rep++) {
      int row = rep * 64 + srow;
      gl_lds16(&BT[(long)row * K + kt + skk], &Bs[rep * 2048 + tid * 8]);
    }
    __syncthreads();
    bf16x8 af[4], bfr[4];
#pragma unroll
    for (int mi = 0; mi < 4; mi++)
      af[mi] = *(const bf16x8*)&As[(wr * 64 + mi * 16 + lr) * 32 + swz];
#pragma unroll
    for (int ni = 0; ni < 4; ni++)
      bfr[ni] = *(const bf16x8*)&Bs[(wc * 64 + ni * 16 + lr) * 32 + swz];
#pragma unroll
    for (int mi = 0; mi < 4; mi++)
#pragma unroll
      for (int ni = 0; ni < 4; ni++)
        acc[mi][ni] =
            __builtin_amdgcn_mfma_f32_16x16x32_bf16(af[mi], bfr[ni], acc[mi][ni], 0, 0, 0);
    __syncthreads();
  }
#pragma unroll
  for (int mi = 0; mi < 4; mi++) {
#pragma unroll
    for (int r = 0; r < 4; r++) {
      int e = m0 + wr * 64 + mi * 16 + lk * 4 + r;
#pragma unroll
      for (int ni = 0; ni < 4; ni++) {
        int col = wc * 64 + ni * 16 + lr;
        int tgt = (col < 64) ? senders[e] : receivers[e];
        atomicAdd(&accb[(long)tgt * 64 + (col & 63)], acc[mi][ni][r]);
      }
    }
  }
}

// ---------- final node MLP, pure f32 (validated) ----------
__global__ __launch_bounds__(256) void k_final(const float* __restrict__ nodes,
                                               const float* __restrict__ g,
                                               const float* __restrict__ nW1,
                                               const float* __restrict__ nb1,
                                               const float* __restrict__ nW2,
                                               const float* __restrict__ nb2,
                                               const float* __restrict__ zpre,
                                               float* __restrict__ out0) {
  __shared__ float h2[64 * 64];
  __shared__ float gb[64];
  const int tid = threadIdx.x;
  const long n0 = (long)blockIdx.x * 64;
  if (tid < 64) {
    float s = nb1[tid];
#pragma unroll
    for (int j = 0; j < 8; j++) s += g[j] * nW1[(long)(8256 + j) * 64 + tid];
    gb[tid] = s;
  }
  __syncthreads();
#pragma unroll 2
  for (int rep = 0; rep < 16; rep++) {
    int idx = rep * 256 + tid;
    int i = idx >> 6, c = idx & 63;
    float z = gb[c] + zpre[(n0 + i) * 64 + c];
    const float* nr = nodes + (n0 + i) * 64;
#pragma unroll 8
    for (int k = 0; k < 64; k++) z += nr[k] * nW1[(long)k * 64 + c];
    h2[idx] = fmaxf(z, 0.f);
  }
  __syncthreads();
#pragma unroll 2
  for (int rep = 0; rep < 16; rep++) {
    int idx = rep * 256 + tid;
    int i = idx >> 6, c = idx & 63;
    float z = nb2[c];
#pragma unroll 8
    for (int k = 0; k < 64; k++) z += h2[i * 64 + k] * nW2[(long)k * 64 + c];
    out0[(n0 + i) * 64 + c] = fmaxf(z, 0.f);
  }
}

extern "C" void kernel_launch(void* const* d_in, const int* in_sizes, int n_in,
                              void* d_out, int out_size, void* d_ws, size_t ws_size,
                              hipStream_t stream) {
  const float* nodes = (const float*)d_in[0];
  const float* edges = (const float*)d_in[1];
  const float* g = (const float*)d_in[2];
  const int* senders = (const int*)d_in[3];
  const int* receivers = (const int*)d_in[4];
  const float* eW1 = (const float*)d_in[5];
  const float* eb1 = (const float*)d_in[6];
  const float* eW2 = (const float*)d_in[7];
  const float* eb2 = (const float*)d_in[8];
  const float* nW1 = (const float*)d_in[9];
  const float* nb1 = (const float*)d_in[10];
  const float* nW2 = (const float*)d_in[11];
  const float* nb2 = (const float*)d_in[12];

  char* ws = (char*)d_ws;
  u16* eW1T = (u16*)(ws + 0);        // [4096][160] bf16, dies after G1
  float* accb = (float*)(ws + 0);    // [8192][64] f32, live after memset (post-G1)
  u16* ein = (u16*)(ws + 2097152);   // [4096][160] bf16, dies after G1
  u16* nWmT = (u16*)(ws + 2097152);  // [128][4096] bf16, written after G1
  u16* eW2T = (u16*)(ws + 3407872);  // [4096][4096] bf16
  u16* h = (u16*)(ws + 36962304);    // [4096][4096] bf16 (ends 70.5MB)

  float* out_nodes = (float*)d_out;
  float* out_edges = (float*)d_out + 524288;

  dim3 b256(256);
  k_transpose<<<dim3(3, 64), b256, 0, stream>>>(eW1, eW1T, 152, 4096, 160);
  k_transpose<<<dim3(64, 64), b256, 0, stream>>>(eW2, eW2T, 4096, 4096, 4096);
  k_build_ein<<<4096, 192, 0, stream>>>(edges, nodes, g, senders, receivers, ein);

  k_mgemm<0><<<dim3(32, 32), b256, 0, stream>>>(ein, eW1T, eb1, h, 4096, 4096, 160);

  // ein/eW1T dead: build nWmT + clear accb before scatter.
  k_transpose<<<dim3(64, 1), b256, 0, stream>>>(nW1 + 64 * 64, nWmT, 4096, 64, 4096);
  k_transpose<<<dim3(64, 1), b256, 0, stream>>>(nW1 + 4160 * 64, nWmT + (long)64 * 4096,
                                                4096, 64, 4096);
  hipMemsetAsync(accb, 0, 8192 * 64 * 4, stream);

  k_gemm256<<<dim3(256), dim3(512), 0, stream>>>(h, eW2T, eb2, out_edges, 4096, 4096);

  k_scatter_m<<<dim3(32, 8), b256, 0, stream>>>(out_edges, nWmT, senders, receivers, accb);
  k_final<<<128, b256, 0, stream>>>(nodes, g, nW1, nb1, nW2, nb2, accb, out_nodes);
}